// Round 3
// baseline (7159.366 us; speedup 1.0000x reference)
//
#include <hip/hip_runtime.h>
#include <cmath>

// LSTM decoder: B=32, T=128, D=512, UNITS=1024, VOCAB=32000.
// Round 2:
//  - Fused persistent scan (1 kernel, manual grid barrier, U in LDS, c in regs)
//  - Phase 3: single fp16 MFMA (268 GF instead of 805 GF split-product)
//  - Phase 3 grid remap (m fast) for B-panel L2/L3 reuse: FETCH 3.1GB -> ~0.2GB

#define BB 32
#define TT 128
#define DD 512
#define UU 1024
#define GG 4096   // 4*UU
#define VV 32000

typedef __attribute__((ext_vector_type(8))) short short8_t;     // 16 B
typedef __attribute__((ext_vector_type(8))) _Float16 f16x8;
typedef __attribute__((ext_vector_type(4))) float f32x4;

// ---------------------------------------------------------------------------
// fp32 tiled GEMM (phase 1): C[M,N] = A[M,K] @ B[K,N] + bias[N]
// 128x128 tile, 256 threads, 8x8 micro-tile, BK=8.  (validated round 1)
// ---------------------------------------------------------------------------
__global__ __launch_bounds__(256, 2) void gemm128(
    const float* __restrict__ A, const float* __restrict__ Bm,
    const float* __restrict__ bias, float* __restrict__ C,
    int M, int N, int K) {
  __shared__ float As[8][128];
  __shared__ float Bs[8][128];
  const int tid = threadIdx.x;
  const int m0 = blockIdx.y * 128;
  const int n0 = blockIdx.x * 128;
  const int a_r = tid >> 1, a_k4 = (tid & 1) * 4;
  const int b_k = tid >> 5, b_n4 = (tid & 31) * 4;
  const int mm = (tid & 15) * 4;
  const int nn = (tid >> 4) * 4;
  float acc[8][8];
#pragma unroll
  for (int i = 0; i < 8; ++i)
#pragma unroll
    for (int j = 0; j < 8; ++j) acc[i][j] = 0.f;

  for (int k0 = 0; k0 < K; k0 += 8) {
    const float4 av = *(const float4*)(A + (size_t)(m0 + a_r) * K + k0 + a_k4);
    const float4 bv = *(const float4*)(Bm + (size_t)(k0 + b_k) * N + n0 + b_n4);
    __syncthreads();
    As[a_k4 + 0][a_r] = av.x;
    As[a_k4 + 1][a_r] = av.y;
    As[a_k4 + 2][a_r] = av.z;
    As[a_k4 + 3][a_r] = av.w;
    *(float4*)(&Bs[b_k][b_n4]) = bv;
    __syncthreads();
#pragma unroll
    for (int k = 0; k < 8; ++k) {
      const float4 a0 = *(const float4*)(&As[k][mm]);
      const float4 a1 = *(const float4*)(&As[k][mm + 64]);
      const float4 q0 = *(const float4*)(&Bs[k][nn]);
      const float4 q1 = *(const float4*)(&Bs[k][nn + 64]);
      const float ar[8] = {a0.x, a0.y, a0.z, a0.w, a1.x, a1.y, a1.z, a1.w};
      const float br[8] = {q0.x, q0.y, q0.z, q0.w, q1.x, q1.y, q1.z, q1.w};
#pragma unroll
      for (int i = 0; i < 8; ++i)
#pragma unroll
        for (int j = 0; j < 8; ++j) acc[i][j] += ar[i] * br[j];
    }
  }
  const float4 bi0 = *(const float4*)(bias + n0 + nn);
  const float4 bi1 = *(const float4*)(bias + n0 + nn + 64);
  const float bia[8] = {bi0.x, bi0.y, bi0.z, bi0.w, bi1.x, bi1.y, bi1.z, bi1.w};
#pragma unroll
  for (int i = 0; i < 8; ++i) {
    const int m = m0 + (i < 4 ? mm + i : mm + 60 + i);
    float* cp = C + (size_t)m * N + n0;
    float4 v0 = {acc[i][0] + bia[0], acc[i][1] + bia[1], acc[i][2] + bia[2], acc[i][3] + bia[3]};
    float4 v1 = {acc[i][4] + bia[4], acc[i][5] + bia[5], acc[i][6] + bia[6], acc[i][7] + bia[7]};
    *(float4*)(cp + nn) = v0;
    *(float4*)(cp + nn + 64) = v1;
  }
}

// ---------------------------------------------------------------------------
// Wd [K=1024][V=32000] f32 -> WdT [V][K] f16 (k-contiguous), 64x64 LDS tiles.
// ---------------------------------------------------------------------------
__global__ __launch_bounds__(256) void convert_wd(
    const float* __restrict__ Wd, unsigned short* __restrict__ Bh) {
  __shared__ float tile[64][65];
  const int tid = threadIdx.x;
  const int tx = tid & 63, ty = tid >> 6;
  const int n0 = blockIdx.x * 64, k0 = blockIdx.y * 64;
#pragma unroll 4
  for (int r = 0; r < 16; ++r) {
    const int k = ty * 16 + r;
    tile[k][tx] = Wd[(size_t)(k0 + k) * VV + n0 + tx];
  }
  __syncthreads();
#pragma unroll 4
  for (int r = 0; r < 16; ++r) {
    const int n = ty * 16 + r;
    const float v = tile[tx][n];
    Bh[(size_t)(n0 + n) * UU + k0 + tx] =
        __builtin_bit_cast(unsigned short, (_Float16)v);
  }
}

// ---------------------------------------------------------------------------
// Um [1024][4096] f32 -> UT [4096][1024] f32 (transpose), 64x64 LDS tiles.
// ---------------------------------------------------------------------------
__global__ __launch_bounds__(256) void transpose_u(
    const float* __restrict__ Um, float* __restrict__ UT) {
  __shared__ float tile[64][65];
  const int tid = threadIdx.x;
  const int tx = tid & 63, ty = tid >> 6;
  const int c0 = blockIdx.x * 64, k0 = blockIdx.y * 64;
#pragma unroll 4
  for (int r = 0; r < 16; ++r) {
    const int k = ty * 16 + r;
    tile[k][tx] = Um[(size_t)(k0 + k) * GG + c0 + tx];
  }
  __syncthreads();
#pragma unroll 4
  for (int r = 0; r < 16; ++r) {
    const int c = ty * 16 + r;
    UT[(size_t)(c0 + c) * UU + k0 + tx] = tile[tx][c];
  }
}

// ---------------------------------------------------------------------------
// Prep: hT0[u][b] = h0[b][u]; mT[g][k][b] = masks[g][b][k]; zero barrier cnt.
// grid 512 x 256 covers 131072.
// ---------------------------------------------------------------------------
__global__ __launch_bounds__(256) void prep_kernel(
    const float* __restrict__ h0, const float* __restrict__ masks,
    float* __restrict__ hT0, float* __restrict__ mT, unsigned* __restrict__ cnt) {
  const int i = blockIdx.x * 256 + threadIdx.x;
  if (i < BB * UU)
    hT0[i] = h0[(i & 31) * UU + (i >> 5)];   // hT[u][b]
  // mT: i over 4*1024*32
  const int g = i >> 15, k = (i >> 5) & 1023, b = i & 31;
  mT[i] = masks[((size_t)g * BB + b) * UU + k];
  if (i == 0) *cnt = 0u;
}

// ---------------------------------------------------------------------------
// Fused LSTM scan: ONE kernel, 256 blocks x 256 threads, persistent.
// Block owns 4 u-columns x 4 gates (16 U-cols, 64 KB LDS, resident all steps).
// Thread (bq,cq=g,kc): 4b x 4u partials over a 128-k chunk; LDS reduce over
// 8 kc; 128 finalize threads own (b,uu) with c-state in registers.
// Grid barrier: monotonic atomic counter, agent scope.
// ---------------------------------------------------------------------------
__global__ __launch_bounds__(256) void lstm_scan(
    const float* __restrict__ xw,    // [B*T][4096], row = b*T+t
    const float* __restrict__ UT,    // [4096][1024] (col-major U)
    const float* __restrict__ mT,    // [4][1024][32]
    float* __restrict__ hT,          // [2][1024][32] double buffer (buf0 init)
    const float* __restrict__ c0,    // [32][1024]
    unsigned short* __restrict__ hs16,  // [B*T][1024] f16
    float* __restrict__ outH, float* __restrict__ outC,
    unsigned* __restrict__ cnt) {
  __shared__ float Us[1024][16];         // [k][c], c = g*4+uu   (64 KB)
  __shared__ float red2[8 * 4 * 132];    // [kc][g][b*4+uu] padded (16.9 KB)

  const int tid = threadIdx.x;
  const int bq = tid & 7;          // b-quad
  const int cq = (tid >> 3) & 3;   // gate
  const int kc = tid >> 5;         // k-chunk (128 wide)
  const int b0 = bq * 4;
  const int u0 = blockIdx.x * 4;   // block's u window

  // ---- load U slice into LDS (one-time): 16 cols x 1024 k ----
#pragma unroll
  for (int c = 0; c < 16; ++c) {
    const int g = c >> 2, uu = c & 3;
    const float4 v = *(const float4*)(UT + ((size_t)g * UU + u0 + uu) * UU + tid * 4);
#pragma unroll
    for (int j = 0; j < 4; ++j) Us[tid * 4 + j][c] = (&v.x)[j];
  }
  __syncthreads();

  // ---- per-finalize-thread persistent state ----
  const int fb = tid >> 2, fu = tid & 3;   // finalize (b, uu) for tid<128
  float c_reg = 0.f;
  if (tid < 128) c_reg = c0[fb * UU + u0 + fu];

  const float* mrow = mT + (size_t)cq * (UU * BB);
  const unsigned nblk = gridDim.x;

  for (int t = 0; t < TT; ++t) {
    const float* hin = hT + (size_t)(t & 1) * (UU * BB);
    float* hout = hT + (size_t)((t + 1) & 1) * (UU * BB);

    // ---- partial GEMV: acc[4b][4u] over this thread's 128-k chunk ----
    float acc[4][4];
#pragma unroll
    for (int i = 0; i < 4; ++i)
#pragma unroll
      for (int j = 0; j < 4; ++j) acc[i][j] = 0.f;

    const int kbeg = kc * 128;
#pragma unroll 4
    for (int k = kbeg; k < kbeg + 128; ++k) {
      const float4 h4 = *(const float4*)(hin + k * 32 + b0);
      const float4 m4 = *(const float4*)(mrow + k * 32 + b0);
      const float hm0 = h4.x * m4.x, hm1 = h4.y * m4.y;
      const float hm2 = h4.z * m4.z, hm3 = h4.w * m4.w;
#pragma unroll
      for (int j = 0; j < 4; ++j) {
        const float uv = Us[k][cq * 4 + j];
        acc[0][j] += hm0 * uv;
        acc[1][j] += hm1 * uv;
        acc[2][j] += hm2 * uv;
        acc[3][j] += hm3 * uv;
      }
    }

    // ---- reduce over kc via LDS ----
    __syncthreads();   // red2 free (prev finalize done via last barrier)
#pragma unroll
    for (int i = 0; i < 4; ++i)
#pragma unroll
      for (int j = 0; j < 4; ++j)
        red2[(kc * 4 + cq) * 132 + (b0 + i) * 4 + j] = acc[i][j];
    __syncthreads();

    // ---- finalize: 128 threads own (b,uu) ----
    if (tid < 128) {
      const float* xwp = xw + ((size_t)(fb * TT + t)) * GG + u0 + fu;
      float z[4];
#pragma unroll
      for (int g = 0; g < 4; ++g) {
        float s = 0.f;
#pragma unroll
        for (int k8 = 0; k8 < 8; ++k8) s += red2[(k8 * 4 + g) * 132 + tid];
        z[g] = s + xwp[(size_t)g * UU];
      }
      const float ig = 1.f / (1.f + expf(-z[0]));
      const float fg = 1.f / (1.f + expf(-z[1]));
      const float cc = tanhf(z[2]);
      const float og = 1.f / (1.f + expf(-z[3]));
      const float cnew = fg * c_reg + ig * cc;
      const float hnew = og * tanhf(cnew);
      c_reg = cnew;
      hout[(u0 + fu) * 32 + fb] = hnew;
      hs16[((size_t)(fb * TT + t)) * UU + u0 + fu] =
          __builtin_bit_cast(unsigned short, (_Float16)hnew);
      if (t == TT - 1) {
        outH[fb * UU + u0 + fu] = hnew;
        outC[fb * UU + u0 + fu] = cnew;
      }
    }

    // ---- grid barrier (skip after last step) ----
    if (t < TT - 1) {
      __syncthreads();
      if (tid == 0) {
        __threadfence();  // release this block's h writes to agent scope
        __hip_atomic_fetch_add(cnt, 1u, __ATOMIC_RELEASE, __HIP_MEMORY_SCOPE_AGENT);
        const unsigned target = (unsigned)(t + 1) * nblk;
        while (__hip_atomic_load(cnt, __ATOMIC_ACQUIRE, __HIP_MEMORY_SCOPE_AGENT) < target) {}
      }
      __syncthreads();
      __threadfence();    // acquire side: invalidate stale cached h lines
    }
  }
}

// ---------------------------------------------------------------------------
// Phase 3: logits[4096][32000] = hs16 @ WdT^T + bd.  fp16 single MFMA.
// 128x128 tile, BK=32, 4 waves (2x2 of 64x64), 16x16x32 f16.
// Grid: x = m-tile (32, FAST) so concurrent blocks share B panels via L2/L3.
// ---------------------------------------------------------------------------
__global__ __launch_bounds__(256, 2) void gemm_f16_logits(
    const unsigned short* __restrict__ Ah, const unsigned short* __restrict__ Bh,
    const float* __restrict__ bias, float* __restrict__ C) {
  __shared__ unsigned short As[128][40];
  __shared__ unsigned short Bs[128][40];
  const int tid = threadIdx.x;
  const int lane = tid & 63;
  const int wave = tid >> 6;
  const int wm = wave >> 1, wn = wave & 1;
  const int q = lane >> 4, l15 = lane & 15;
  const int m0 = blockIdx.x * 128;   // m fast
  const int n0 = blockIdx.y * 128;
  const int srow = tid >> 2;
  const int sk = (tid & 3) * 8;

  f32x4 acc[4][4];
#pragma unroll
  for (int mf = 0; mf < 4; ++mf)
#pragma unroll
    for (int nf = 0; nf < 4; ++nf) acc[mf][nf] = f32x4{0.f, 0.f, 0.f, 0.f};

  const size_t arow0 = (size_t)(m0 + srow) * UU + sk;
  const size_t arow1 = (size_t)(m0 + 64 + srow) * UU + sk;
  const size_t brow0 = (size_t)(n0 + srow) * UU + sk;
  const size_t brow1 = (size_t)(n0 + 64 + srow) * UU + sk;

  for (int k0 = 0; k0 < UU; k0 += 32) {
    const short8_t ra0 = *(const short8_t*)(Ah + arow0 + k0);
    const short8_t ra1 = *(const short8_t*)(Ah + arow1 + k0);
    const short8_t rb0 = *(const short8_t*)(Bh + brow0 + k0);
    const short8_t rb1 = *(const short8_t*)(Bh + brow1 + k0);
    __syncthreads();
    *(short8_t*)&As[srow][sk] = ra0;
    *(short8_t*)&As[64 + srow][sk] = ra1;
    *(short8_t*)&Bs[srow][sk] = rb0;
    *(short8_t*)&Bs[64 + srow][sk] = rb1;
    __syncthreads();

    f16x8 ah[4], bh[4];
#pragma unroll
    for (int f = 0; f < 4; ++f) {
      ah[f] = __builtin_bit_cast(f16x8, *(const short8_t*)&As[wm * 64 + f * 16 + l15][q * 8]);
      bh[f] = __builtin_bit_cast(f16x8, *(const short8_t*)&Bs[wn * 64 + f * 16 + l15][q * 8]);
    }
#pragma unroll
    for (int mf = 0; mf < 4; ++mf)
#pragma unroll
      for (int nf = 0; nf < 4; ++nf)
        acc[mf][nf] = __builtin_amdgcn_mfma_f32_16x16x32_f16(ah[mf], bh[nf], acc[mf][nf], 0, 0, 0);
  }

#pragma unroll
  for (int nf = 0; nf < 4; ++nf) {
    const int n = n0 + wn * 64 + nf * 16 + l15;
    const float bia = bias[n];
#pragma unroll
    for (int mf = 0; mf < 4; ++mf) {
      const int mbase = m0 + wm * 64 + mf * 16 + q * 4;
#pragma unroll
      for (int r = 0; r < 4; ++r)
        C[(size_t)(mbase + r) * VV + n] = acc[mf][nf][r] + bia;
    }
  }
}

// ---------------------------------------------------------------------------
extern "C" void kernel_launch(void* const* d_in, const int* in_sizes, int n_in,
                              void* d_out, int out_size, void* d_ws, size_t ws_size,
                              hipStream_t stream) {
  const float* x     = (const float*)d_in[0];
  const float* h0    = (const float*)d_in[1];
  const float* c0    = (const float*)d_in[2];
  const float* W     = (const float*)d_in[3];
  const float* Um    = (const float*)d_in[4];
  const float* bvec  = (const float*)d_in[5];
  const float* Wd    = (const float*)d_in[6];
  const float* bd    = (const float*)d_in[7];
  const float* masks = (const float*)d_in[8];

  float* out = (float*)d_out;
  float* logits = out;                          // [B,T,V]
  float* outH = out + (size_t)BB * TT * VV;
  float* outC = outH + (size_t)BB * UU;
  float* xw = logits;   // stash: fully consumed by scan before phase 3 writes

  // workspace layout (~91.5 MB; round-1 profile proves ws >= 141 MB)
  char* ws = (char*)d_ws;
  unsigned short* WdT16 = (unsigned short*)ws;      ws += (size_t)VV * UU * 2;
  unsigned short* hs16  = (unsigned short*)ws;      ws += (size_t)BB * TT * UU * 2;
  float* UT   = (float*)ws;                         ws += (size_t)GG * UU * 4;
  float* mT   = (float*)ws;                         ws += (size_t)4 * UU * BB * 4;
  float* hT   = (float*)ws;                         ws += (size_t)2 * UU * BB * 4;
  unsigned* cnt = (unsigned*)ws;

  prep_kernel<<<512, 256, 0, stream>>>(h0, masks, hT, mT, cnt);
  transpose_u<<<dim3(GG / 64, UU / 64), 256, 0, stream>>>(Um, UT);
  convert_wd<<<dim3(VV / 64, UU / 64), 256, 0, stream>>>(Wd, WdT16);

  // Phase 1: xw = x @ W + b    (M=4096, N=4096, K=512) fp32 VALU GEMM
  gemm128<<<dim3(GG / 128, (BB * TT) / 128), 256, 0, stream>>>(
      x, W, bvec, xw, BB * TT, GG, DD);

  // Phase 2: fused persistent scan (single launch, 128 internal grid barriers)
  lstm_scan<<<256, 256, 0, stream>>>(xw, UT, mT, hT, c0, hs16, outH, outC, cnt);

  // Phase 3: logits = hs @ Wd + bd   (fp16 MFMA, m-fast grid for B reuse)
  gemm_f16_logits<<<dim3((BB * TT) / 128, VV / 128), 256, 0, stream>>>(
      hs16, WdT16, bd, logits);
}